// Round 4
// baseline (359.442 us; speedup 1.0000x reference)
//
#include <hip/hip_runtime.h>
#include <hip/hip_cooperative_groups.h>

namespace cg = cooperative_groups;

typedef __attribute__((ext_vector_type(8))) short svec8;
typedef __attribute__((ext_vector_type(4))) float fvec4;

#define NB    4096
#define NN    6
#define FF    512
#define CC    256
#define KFULL 1024
#define MROWS (NB*NN)                 // 24576
#define AD_HALF ((size_t)MROWS*CC)    // 6291456 elements
#define NTOT  (NB*NN*NN)              // 147456
#define GRID  512

#define GLOAD16(gp, lp) __builtin_amdgcn_global_load_lds(                      \
    (const __attribute__((address_space(1))) unsigned int*)(gp),               \
    (__attribute__((address_space(3))) unsigned int*)(lp), 16, 0, 0)

__device__ __forceinline__ unsigned short f2bf(float f) {
    unsigned u = __float_as_uint(f);
    u += 0x7FFFu + ((u >> 16) & 1u);   // round-to-nearest-even
    return (unsigned short)(u >> 16);
}
__device__ __forceinline__ float bf2f(unsigned short h) {
    return __uint_as_float(((unsigned)h) << 16);
}

// ==================== fused cooperative kernel ====================
// 512 blocks x 256 thr, 2 blocks/CU guaranteed. Phases:
// 0: conv_w fp32->bf16 + zero stats | 1: GEMM (BM=96, one tile/block)
// 2: per-channel stats | 3: normalize + write out
__global__ __launch_bounds__(256, 2) void k_fused(
        const float* __restrict__ x,
        const float* __restrict__ conv_w,
        const float* __restrict__ conv_b,
        const float* __restrict__ gamma,
        const float* __restrict__ beta,
        unsigned short* __restrict__ wbf,
        unsigned short* __restrict__ AD,
        float* __restrict__ stats,
        float* __restrict__ out) {
    cg::grid_group grid = cg::this_grid();
    __shared__ __align__(16) char lds[45056];   // A: 96x64 bf16 = 12KB @0, B: 256x64 bf16 = 32KB @12288
    const int tid = threadIdx.x;
    const int blk = blockIdx.x;

    // ---------------- phase 0 ----------------
    {
        int g = blk * 256 + tid;          // 131072 threads >= 65536 vec4 chunks
        if (g < 65536) {
            fvec4 v = *(const fvec4*)(conv_w + (size_t)g * 4);
            unsigned long long pk = (unsigned long long)f2bf(v[0])
                                  | ((unsigned long long)f2bf(v[1]) << 16)
                                  | ((unsigned long long)f2bf(v[2]) << 32)
                                  | ((unsigned long long)f2bf(v[3]) << 48);
            *(unsigned long long*)(wbf + (size_t)g * 4) = pk;
        }
        if (g < 512) stats[g] = 0.f;
    }
    __threadfence();
    grid.sync();

    // ---------------- phase 1: GEMM, BM=96 ----------------
    {
        const int s = blk & 1;
        const int mtile = blk >> 1;       // 0..255, covers 256*96 = 24576 rows
        const int wv = tid >> 6;

        const int slot = tid & 7;
        const int arow0 = tid >> 3;       // 0..31
        const float* aptr[3];
#pragma unroll
        for (int i = 0; i < 3; ++i) {
            int row = arow0 + 32 * i;
            int m = mtile * 96 + row;
            int b = m / 6;
            int jn = m - b * 6;
            aptr[i] = x + ((size_t)((b * 2 + s) * 6 + jn)) * FF + slot * 8;
        }
        const int a_lds0 = arow0 * 128 + ((slot * 16) ^ ((arow0 & 7) << 4));

        const unsigned short* bsrc[8];
        char* bdst[8];
#pragma unroll
        for (int i = 0; i < 8; ++i) {
            int ci = i * 256 + tid;
            int row = ci >> 3;
            int xslot = ci & 7;
            bsrc[i] = wbf + (size_t)row * KFULL + s * FF + ((xslot ^ (row & 7)) << 3);
            bdst[i] = lds + 12288 + i * 4096 + wv * 1024;
        }

        const int l = tid & 63;
        const int lrow = l & 15;
        const int lk = l >> 4;
        int abase[2], bbase[2];
#pragma unroll
        for (int ks = 0; ks < 2; ++ks) {
            int kb = ks * 64 + lk * 16;
            int xr = kb ^ ((lrow & 7) << 4);
            abase[ks] = lrow * 128 + xr;
            bbase[ks] = 12288 + (wv * 64 + lrow) * 128 + xr;
        }

        const fvec4 vzero = {0.f, 0.f, 0.f, 0.f};
        fvec4 acc[6][4];
#pragma unroll
        for (int mi = 0; mi < 6; ++mi)
#pragma unroll
            for (int ni = 0; ni < 4; ++ni) acc[mi][ni] = vzero;

        fvec4 alo[3], ahi[3];
#pragma unroll
        for (int i = 0; i < 3; ++i) {
            alo[i] = *(const fvec4*)(aptr[i]);
            ahi[i] = *(const fvec4*)(aptr[i] + 4);
        }

        for (int kt = 0; kt < 8; ++kt) {
            const int k0 = kt * 64;
#pragma unroll
            for (int i = 0; i < 3; ++i) {
                svec8 v;
                v[0] = (short)f2bf(alo[i][0]); v[1] = (short)f2bf(alo[i][1]);
                v[2] = (short)f2bf(alo[i][2]); v[3] = (short)f2bf(alo[i][3]);
                v[4] = (short)f2bf(ahi[i][0]); v[5] = (short)f2bf(ahi[i][1]);
                v[6] = (short)f2bf(ahi[i][2]); v[7] = (short)f2bf(ahi[i][3]);
                *(svec8*)(lds + a_lds0 + i * 4096) = v;
            }
#pragma unroll
            for (int i = 0; i < 8; ++i) GLOAD16(bsrc[i] + k0, bdst[i]);
            __syncthreads();
            if (kt < 7) {
#pragma unroll
                for (int i = 0; i < 3; ++i) {
                    const float* p = aptr[i] + (kt + 1) * 64;
                    alo[i] = *(const fvec4*)(p);
                    ahi[i] = *(const fvec4*)(p + 4);
                }
            }
#pragma unroll
            for (int ks = 0; ks < 2; ++ks) {
                svec8 af[6], bfr[4];
#pragma unroll
                for (int mi = 0; mi < 6; ++mi) af[mi] = *(const svec8*)(lds + abase[ks] + mi * 2048);
#pragma unroll
                for (int ni = 0; ni < 4; ++ni) bfr[ni] = *(const svec8*)(lds + bbase[ks] + ni * 2048);
#pragma unroll
                for (int mi = 0; mi < 6; ++mi)
#pragma unroll
                    for (int ni = 0; ni < 4; ++ni)
                        acc[mi][ni] = __builtin_amdgcn_mfma_f32_16x16x32_bf16(
                            af[mi], bfr[ni], acc[mi][ni], 0, 0, 0);
            }
            __syncthreads();
        }

        unsigned short* op = AD + (size_t)s * AD_HALF;
#pragma unroll
        for (int mi = 0; mi < 6; ++mi) {
#pragma unroll
            for (int j = 0; j < 4; ++j) {
                int r = mi * 16 + lk * 4 + j;
                size_t m = (size_t)(mtile * 96 + r);
#pragma unroll
                for (int ni = 0; ni < 4; ++ni) {
                    int c = wv * 64 + ni * 16 + lrow;
                    op[m * 256 + c] = f2bf(acc[mi][ni][j]);
                }
            }
        }
    }
    __threadfence();
    grid.sync();

    // ---------------- phase 2: per-channel stats (256 blocks x 16 batches) ----------------
    if (blk < 256) {
        const int c = tid;
        const float bias = conv_b[c];
        float s = 0.f, s2 = 0.f;
        const int b0 = blk * 16;
        for (int bb = 0; bb < 16; ++bb) {
            const size_t base = (size_t)(b0 + bb) * (6 * 256) + c;
            const unsigned short* ga = AD + base;
            const unsigned short* gd = AD + AD_HALF + base;
            float a[6], d[6];
#pragma unroll
            for (int j = 0; j < 6; ++j) { a[j] = bf2f(ga[j * 256]); d[j] = bf2f(gd[j * 256]); }
#pragma unroll
            for (int j = 0; j < 6; ++j) {
                float aj = a[j] + bias;
#pragma unroll
                for (int e = 0; e < 6; ++e) {
                    float h = fmaxf(aj + d[e], 0.f);
                    s += h;
                    s2 = fmaf(h, h, s2);
                }
            }
        }
        atomicAdd(&stats[c], s);
        atomicAdd(&stats[256 + c], s2);
    }
    __threadfence();
    grid.sync();

    // ---------------- phase 3: normalize + write output ----------------
    {
        float (*Al)[260] = (float(*)[260])lds;            //  6240 B
        float (*Dl)[260] = (float(*)[260])(lds + 6240);   //  6240 B
        float* sc = (float*)(lds + 12480);
        float* sh = (float*)(lds + 13504);
        float* bi = (float*)(lds + 14528);

        const float inv_n = 1.0f / (float)NTOT;
        float mean = stats[tid] * inv_n;
        float var = fmaf(-mean, mean, stats[256 + tid] * inv_n);
        float scale = gamma[tid] * rsqrtf(var + 1e-5f);
        sc[tid] = scale;
        sh[tid] = fmaf(-mean, scale, beta[tid]);
        bi[tid] = conv_b[tid];

        for (int b = blk; b < NB; b += GRID) {
            __syncthreads();
            const unsigned short* ga = AD + (size_t)b * 1536;
            const unsigned short* gd = AD + AD_HALF + (size_t)b * 1536;
#pragma unroll
            for (int i = 0; i < 6; ++i) {
                Al[i][tid] = bf2f(ga[i * 256 + tid]);
                Dl[i][tid] = bf2f(gd[i * 256 + tid]);
            }
            __syncthreads();
            float* ob = out + (size_t)b * 9216;
#pragma unroll
            for (int it = 0; it < 36; ++it) {
                int idx = it * 256 + tid;
                int c = idx / 36;
                int r = idx - c * 36;
                int ii = r / 6;
                int j = r - ii * 6;
                int d = j - ii; if (d < 0) d += 6;
                float h = fmaxf(Al[j][c] + Dl[d][c] + bi[c], 0.f);
                __builtin_nontemporal_store(fmaf(h, sc[c], sh[c]), ob + idx);
            }
        }
    }
}

// ==================== fallback path (proven R2 kernels) ====================
__global__ __launch_bounds__(256) void k_wconv(const float* __restrict__ w,
                                               unsigned short* __restrict__ wbf) {
    int i = (blockIdx.x * 256 + threadIdx.x) * 4;
    fvec4 v = *(const fvec4*)(w + i);
    unsigned long long pk = (unsigned long long)f2bf(v[0])
                          | ((unsigned long long)f2bf(v[1]) << 16)
                          | ((unsigned long long)f2bf(v[2]) << 32)
                          | ((unsigned long long)f2bf(v[3]) << 48);
    *(unsigned long long*)(wbf + i) = pk;
}

__global__ __launch_bounds__(256) void k_gemm(const float* __restrict__ x,
                                              const unsigned short* __restrict__ wbf,
                                              unsigned short* __restrict__ AD) {
    __shared__ __align__(16) char lds[40960];
    const int tid = threadIdx.x;
    const int s = blockIdx.x & 1;
    const int mtile = blockIdx.x >> 1;
    const int wv = tid >> 6;

    const int slot = tid & 7;
    const int arow0 = tid >> 3;
    const float* aptr[2];
#pragma unroll
    for (int i = 0; i < 2; ++i) {
        int row = arow0 + 32 * i;
        int m = mtile * 64 + row;
        int b = m / 6;
        int jn = m - b * 6;
        aptr[i] = x + ((size_t)((b * 2 + s) * 6 + jn)) * FF + slot * 8;
    }
    const int a_lds0 = arow0 * 128 + ((slot * 16) ^ ((arow0 & 7) << 4));

    const unsigned short* bsrc[8];
    char* bdst[8];
#pragma unroll
    for (int i = 0; i < 8; ++i) {
        int ci = i * 256 + tid;
        int row = ci >> 3;
        int xslot = ci & 7;
        bsrc[i] = wbf + (size_t)row * KFULL + s * FF + ((xslot ^ (row & 7)) << 3);
        bdst[i] = lds + 8192 + i * 4096 + wv * 1024;
    }

    const int l = tid & 63;
    const int lrow = l & 15;
    const int lk = l >> 4;
    int abase[2], bbase[2];
#pragma unroll
    for (int ks = 0; ks < 2; ++ks) {
        int kb = ks * 64 + lk * 16;
        int xr = kb ^ ((lrow & 7) << 4);
        abase[ks] = lrow * 128 + xr;
        bbase[ks] = 8192 + (wv * 64 + lrow) * 128 + xr;
    }

    const fvec4 vzero = {0.f, 0.f, 0.f, 0.f};
    fvec4 acc[4][4];
#pragma unroll
    for (int mi = 0; mi < 4; ++mi)
#pragma unroll
        for (int ni = 0; ni < 4; ++ni) acc[mi][ni] = vzero;

    fvec4 alo[2], ahi[2];
#pragma unroll
    for (int i = 0; i < 2; ++i) {
        alo[i] = *(const fvec4*)(aptr[i]);
        ahi[i] = *(const fvec4*)(aptr[i] + 4);
    }

    for (int kt = 0; kt < 8; ++kt) {
        const int k0 = kt * 64;
#pragma unroll
        for (int i = 0; i < 2; ++i) {
            svec8 v;
            v[0] = (short)f2bf(alo[i][0]); v[1] = (short)f2bf(alo[i][1]);
            v[2] = (short)f2bf(alo[i][2]); v[3] = (short)f2bf(alo[i][3]);
            v[4] = (short)f2bf(ahi[i][0]); v[5] = (short)f2bf(ahi[i][1]);
            v[6] = (short)f2bf(ahi[i][2]); v[7] = (short)f2bf(ahi[i][3]);
            *(svec8*)(lds + a_lds0 + i * 4096) = v;
        }
#pragma unroll
        for (int i = 0; i < 8; ++i) GLOAD16(bsrc[i] + k0, bdst[i]);
        __syncthreads();
        if (kt < 7) {
#pragma unroll
            for (int i = 0; i < 2; ++i) {
                const float* p = aptr[i] + (kt + 1) * 64;
                alo[i] = *(const fvec4*)(p);
                ahi[i] = *(const fvec4*)(p + 4);
            }
        }
#pragma unroll
        for (int ks = 0; ks < 2; ++ks) {
            svec8 af[4], bfr[4];
#pragma unroll
            for (int mi = 0; mi < 4; ++mi) af[mi] = *(const svec8*)(lds + abase[ks] + mi * 2048);
#pragma unroll
            for (int ni = 0; ni < 4; ++ni) bfr[ni] = *(const svec8*)(lds + bbase[ks] + ni * 2048);
#pragma unroll
            for (int mi = 0; mi < 4; ++mi)
#pragma unroll
                for (int ni = 0; ni < 4; ++ni)
                    acc[mi][ni] = __builtin_amdgcn_mfma_f32_16x16x32_bf16(
                        af[mi], bfr[ni], acc[mi][ni], 0, 0, 0);
        }
        __syncthreads();
    }

    unsigned short* op = AD + (size_t)s * AD_HALF;
#pragma unroll
    for (int mi = 0; mi < 4; ++mi) {
#pragma unroll
        for (int j = 0; j < 4; ++j) {
            int r = mi * 16 + lk * 4 + j;
            size_t m = (size_t)(mtile * 64 + r);
#pragma unroll
            for (int ni = 0; ni < 4; ++ni) {
                int c = wv * 64 + ni * 16 + lrow;
                op[m * 256 + c] = f2bf(acc[mi][ni][j]);
            }
        }
    }
}

__global__ __launch_bounds__(256) void k_stats(const unsigned short* __restrict__ AD,
                                               const float* __restrict__ conv_b,
                                               float* __restrict__ stats) {
    const int c = threadIdx.x;
    const float bias = conv_b[c];
    float s = 0.f, s2 = 0.f;
    const int b0 = blockIdx.x * 8;
    for (int bb = 0; bb < 8; ++bb) {
        const size_t base = (size_t)(b0 + bb) * (6 * 256) + c;
        const unsigned short* ga = AD + base;
        const unsigned short* gd = AD + AD_HALF + base;
        float a[6], d[6];
#pragma unroll
        for (int j = 0; j < 6; ++j) { a[j] = bf2f(ga[j * 256]); d[j] = bf2f(gd[j * 256]); }
#pragma unroll
        for (int j = 0; j < 6; ++j) {
            float aj = a[j] + bias;
#pragma unroll
            for (int e = 0; e < 6; ++e) {
                float h = fmaxf(aj + d[e], 0.f);
                s += h;
                s2 = fmaf(h, h, s2);
            }
        }
    }
    atomicAdd(&stats[c], s);
    atomicAdd(&stats[256 + c], s2);
}

__global__ __launch_bounds__(256) void k_out(const unsigned short* __restrict__ AD,
                                             const float* __restrict__ conv_b,
                                             const float* __restrict__ gamma,
                                             const float* __restrict__ beta,
                                             const float* __restrict__ stats,
                                             float* __restrict__ out) {
    __shared__ float Al[6][260], Dl[6][260];
    __shared__ float sc[256], sh[256], bi[256];
    const int t = threadIdx.x;
    const int b = blockIdx.x;
    const unsigned short* ga = AD + (size_t)b * 1536;
    const unsigned short* gd = AD + AD_HALF + (size_t)b * 1536;
#pragma unroll
    for (int i = 0; i < 6; ++i) {
        Al[i][t] = bf2f(ga[i * 256 + t]);
        Dl[i][t] = bf2f(gd[i * 256 + t]);
    }
    const float inv_n = 1.0f / (float)NTOT;
    float mean = stats[t] * inv_n;
    float var = fmaf(-mean, mean, stats[256 + t] * inv_n);
    float scale = gamma[t] * rsqrtf(var + 1e-5f);
    sc[t] = scale;
    sh[t] = fmaf(-mean, scale, beta[t]);
    bi[t] = conv_b[t];
    __syncthreads();
    float* ob = out + (size_t)b * 9216;
#pragma unroll
    for (int it = 0; it < 36; ++it) {
        int idx = it * 256 + t;
        int c = idx / 36;
        int r = idx - c * 36;
        int ii = r / 6;
        int j = r - ii * 6;
        int d = j - ii; if (d < 0) d += 6;
        float h = fmaxf(Al[j][c] + Dl[d][c] + bi[c], 0.f);
        __builtin_nontemporal_store(fmaf(h, sc[c], sh[c]), ob + idx);
    }
}

extern "C" void kernel_launch(void* const* d_in, const int* in_sizes, int n_in,
                              void* d_out, int out_size, void* d_ws, size_t ws_size,
                              hipStream_t stream) {
    const float* x      = (const float*)d_in[0];
    const float* conv_w = (const float*)d_in[1];
    const float* conv_b = (const float*)d_in[2];
    const float* gamma  = (const float*)d_in[3];
    const float* beta   = (const float*)d_in[4];
    float* out = (float*)d_out;

    char* ws = (char*)d_ws;
    unsigned short* wbf = (unsigned short*)ws;                       // 512 KB
    unsigned short* AD  = (unsigned short*)(ws + 524288);            // 25165824 B
    float* stats        = (float*)(ws + 524288 + 25165824);          // 2 KB

    void* args[] = {(void*)&x, (void*)&conv_w, (void*)&conv_b, (void*)&gamma,
                    (void*)&beta, (void*)&wbf, (void*)&AD, (void*)&stats, (void*)&out};
    hipError_t rc = hipLaunchCooperativeKernel((const void*)k_fused, dim3(GRID),
                                               dim3(256), args, 0, stream);
    if (rc != hipSuccess) {
        // deterministic fallback: proven 4-kernel path
        hipMemsetAsync(stats, 0, 512 * sizeof(float), stream);
        k_wconv<<<256, 256, 0, stream>>>(conv_w, wbf);
        k_gemm<<<768, 256, 0, stream>>>(x, wbf, AD);
        k_stats<<<512, 256, 0, stream>>>(AD, conv_b, stats);
        k_out<<<4096, 256, 0, stream>>>(AD, conv_b, gamma, beta, stats, out);
    }
}

// Round 5
// 76.782 us; speedup vs baseline: 4.6813x; 4.6813x over previous
//
#include <hip/hip_runtime.h>

typedef __attribute__((ext_vector_type(8))) short svec8;
typedef __attribute__((ext_vector_type(4))) float fvec4;

#define NB    4096
#define NN    6
#define FF    512
#define CC    256
#define KFULL 1024
#define MROWS (NB*NN)                 // 24576
#define AD_HALF ((size_t)MROWS*CC)    // 6291456 elements
#define NTOT  (NB*NN*NN)              // 147456

#define GLOAD16(gp, lp) __builtin_amdgcn_global_load_lds(                      \
    (const __attribute__((address_space(1))) unsigned int*)(gp),               \
    (__attribute__((address_space(3))) unsigned int*)(lp), 16, 0, 0)

__device__ __forceinline__ unsigned short f2bf(float f) {
    unsigned u = __float_as_uint(f);
    u += 0x7FFFu + ((u >> 16) & 1u);   // round-to-nearest-even
    return (unsigned short)(u >> 16);
}
__device__ __forceinline__ float bf2f(unsigned short h) {
    return __uint_as_float(((unsigned)h) << 16);
}

// ---------------- kernel 0: conv_w fp32->bf16 + zero stats ----------------
__global__ __launch_bounds__(256) void k_pre(const float* __restrict__ w,
                                             unsigned short* __restrict__ wbf,
                                             float* __restrict__ stats) {
    int g = blockIdx.x * 256 + threadIdx.x;   // grid 256 -> 65536 vec4 chunks
    fvec4 v = *(const fvec4*)(w + (size_t)g * 4);
    unsigned long long pk = (unsigned long long)f2bf(v[0])
                          | ((unsigned long long)f2bf(v[1]) << 16)
                          | ((unsigned long long)f2bf(v[2]) << 32)
                          | ((unsigned long long)f2bf(v[3]) << 48);
    *(unsigned long long*)(wbf + (size_t)g * 4) = pk;
    if (g < 512) stats[g] = 0.f;
}

// ---------------- kernel 1: GEMM both halves + fused per-channel stats ----------------
// grid 256 x 512 thr. Block owns rows [mtile*96, +96) = 16 complete b-groups.
// Pass s=0: A-half (x[b,0], W[:,0:512]); pass s=1: D-half. Same LDS reused.
// 8 waves: col-group cg=wv&3 (64 cols), row-half rh=wv>>2 (48 rows).
// Tail: re-read own AD tile (L2-hot) -> partial stats -> LDS combine -> 2 atomics/c.
__global__ __launch_bounds__(512, 1) void k_gemm_fused(
        const float* __restrict__ x,
        const unsigned short* __restrict__ wbf,
        const float* __restrict__ conv_b,
        unsigned short* __restrict__ AD,
        float* __restrict__ stats) {
    __shared__ __align__(16) char lds[45056];   // A: 96x64 bf16 = 12KB @0, B: 256x64 bf16 = 32KB @12288
    const int tid = threadIdx.x;
    const int mtile = blockIdx.x;               // 0..255
    const int wv = tid >> 6;
    const int cg = wv & 3;
    const int rh = wv >> 2;

    // --- A staging units: unit0 = tid (rows 0..63), unit1 = 512+tid for tid<256 (rows 64..95) ---
    const int row0 = tid >> 3, slot0 = tid & 7;
    const int row1 = 64 + (tid >> 3);           // only tid<256
    const int a_lds_u0 = row0 * 128 + ((slot0 * 16) ^ ((row0 & 7) << 4));
    const int a_lds_u1 = row1 * 128 + ((slot0 * 16) ^ ((row1 & 7) << 4));
    const bool has_u1 = (tid < 256);

    // --- fragment LDS offsets (pass-invariant) ---
    const int l = tid & 63;
    const int lrow = l & 15;
    const int lk = l >> 4;
    int abase[2], bbase[2];
#pragma unroll
    for (int ks = 0; ks < 2; ++ks) {
        int xr = (ks * 64 + lk * 16) ^ ((lrow & 7) << 4);
        abase[ks] = (rh * 48 + lrow) * 128 + xr;
        bbase[ks] = 12288 + (cg * 64 + lrow) * 128 + xr;
    }

    const fvec4 vzero = {0.f, 0.f, 0.f, 0.f};
    fvec4 accA[3][4], accD[3][4];
#pragma unroll
    for (int mi = 0; mi < 3; ++mi)
#pragma unroll
        for (int ni = 0; ni < 4; ++ni) { accA[mi][ni] = vzero; accD[mi][ni] = vzero; }

#pragma unroll
    for (int s = 0; s < 2; ++s) {
        fvec4 (&acc)[3][4] = s ? accD : accA;

        // per-pass global addresses
        int b0 = mtile * 16 + row0 / 6, j0 = row0 % 6;
        const float* aptr0 = x + ((size_t)((b0 * 2 + s) * 6 + j0)) * FF + slot0 * 8;
        int b1 = mtile * 16 + row1 / 6, j1 = row1 % 6;
        const float* aptr1 = x + ((size_t)((b1 * 2 + s) * 6 + j1)) * FF + slot0 * 8;

        const unsigned short* bsrc[4];
        char* bdst[4];
#pragma unroll
        for (int i = 0; i < 4; ++i) {
            int ci = i * 512 + tid;          // 0..2047
            int row = ci >> 3;
            int xslot = ci & 7;
            bsrc[i] = wbf + (size_t)row * KFULL + s * FF + ((xslot ^ (row & 7)) << 3);
            bdst[i] = lds + 12288 + i * 8192 + wv * 1024;   // wave-uniform base
        }

        // prefetch A regs for kt=0
        fvec4 lo0 = *(const fvec4*)aptr0, hi0 = *(const fvec4*)(aptr0 + 4);
        fvec4 lo1 = vzero, hi1 = vzero;
        if (has_u1) { lo1 = *(const fvec4*)aptr1; hi1 = *(const fvec4*)(aptr1 + 4); }

        for (int kt = 0; kt < 8; ++kt) {
            const int k0 = kt * 64;
            {
                svec8 v;
                v[0] = (short)f2bf(lo0[0]); v[1] = (short)f2bf(lo0[1]);
                v[2] = (short)f2bf(lo0[2]); v[3] = (short)f2bf(lo0[3]);
                v[4] = (short)f2bf(hi0[0]); v[5] = (short)f2bf(hi0[1]);
                v[6] = (short)f2bf(hi0[2]); v[7] = (short)f2bf(hi0[3]);
                *(svec8*)(lds + a_lds_u0) = v;
            }
            if (has_u1) {
                svec8 v;
                v[0] = (short)f2bf(lo1[0]); v[1] = (short)f2bf(lo1[1]);
                v[2] = (short)f2bf(lo1[2]); v[3] = (short)f2bf(lo1[3]);
                v[4] = (short)f2bf(hi1[0]); v[5] = (short)f2bf(hi1[1]);
                v[6] = (short)f2bf(hi1[2]); v[7] = (short)f2bf(hi1[3]);
                *(svec8*)(lds + a_lds_u1) = v;
            }
#pragma unroll
            for (int i = 0; i < 4; ++i) GLOAD16(bsrc[i] + k0, bdst[i]);
            __syncthreads();
            if (kt < 7) {
                const float* p0 = aptr0 + (kt + 1) * 64;
                lo0 = *(const fvec4*)p0; hi0 = *(const fvec4*)(p0 + 4);
                if (has_u1) {
                    const float* p1 = aptr1 + (kt + 1) * 64;
                    lo1 = *(const fvec4*)p1; hi1 = *(const fvec4*)(p1 + 4);
                }
            }
#pragma unroll
            for (int ks = 0; ks < 2; ++ks) {
                svec8 af[3], bfr[4];
#pragma unroll
                for (int mi = 0; mi < 3; ++mi) af[mi] = *(const svec8*)(lds + abase[ks] + mi * 2048);
#pragma unroll
                for (int ni = 0; ni < 4; ++ni) bfr[ni] = *(const svec8*)(lds + bbase[ks] + ni * 2048);
#pragma unroll
                for (int mi = 0; mi < 3; ++mi)
#pragma unroll
                    for (int ni = 0; ni < 4; ++ni)
                        acc[mi][ni] = __builtin_amdgcn_mfma_f32_16x16x32_bf16(
                            af[mi], bfr[ni], acc[mi][ni], 0, 0, 0);
            }
            __syncthreads();
        }

        // epilogue for this pass: C/D layout col=lane&15, row=(lane>>4)*4+reg
        unsigned short* op = AD + (size_t)s * AD_HALF;
#pragma unroll
        for (int mi = 0; mi < 3; ++mi) {
#pragma unroll
            for (int j = 0; j < 4; ++j) {
                int r = rh * 48 + mi * 16 + lk * 4 + j;
                size_t m = (size_t)(mtile * 96 + r);
#pragma unroll
                for (int ni = 0; ni < 4; ++ni) {
                    int c = cg * 64 + ni * 16 + lrow;
                    op[m * 256 + c] = f2bf(acc[mi][ni][j]);
                }
            }
        }
    }

    // ---- fused stats tail: re-read own tile (L2-hot), reduce, atomic ----
    asm volatile("s_waitcnt vmcnt(0)" ::: "memory");
    __syncthreads();   // all waves' AD stores drained to L2
    {
        const int c = tid & 255;
        const int half = tid >> 8;
        const float bias = conv_b[c];
        float s1 = 0.f, s2 = 0.f;
        for (int bb = 0; bb < 8; ++bb) {
            int bl = half * 8 + bb;
            size_t m0 = (size_t)(mtile * 96 + bl * 6);
            const unsigned short* ga = AD + m0 * 256 + c;
            const unsigned short* gd = AD + AD_HALF + m0 * 256 + c;
            float a[6], d[6];
#pragma unroll
            for (int j = 0; j < 6; ++j) { a[j] = bf2f(ga[j * 256]); d[j] = bf2f(gd[j * 256]); }
#pragma unroll
            for (int j = 0; j < 6; ++j) {
                float aj = a[j] + bias;
#pragma unroll
                for (int e = 0; e < 6; ++e) {
                    float h = fmaxf(aj + d[e], 0.f);
                    s1 += h;
                    s2 = fmaf(h, h, s2);
                }
            }
        }
        float* red = (float*)lds;
        red[half * 256 + c] = s1;
        red[512 + half * 256 + c] = s2;
        __syncthreads();
        if (tid < 256) {
            atomicAdd(&stats[tid], red[tid] + red[256 + tid]);
            atomicAdd(&stats[256 + tid], red[512 + tid] + red[768 + tid]);
        }
    }
}

// ---------------- kernel 2: normalize + write output ----------------
__global__ __launch_bounds__(256) void k_out(const unsigned short* __restrict__ AD,
                                             const float* __restrict__ conv_b,
                                             const float* __restrict__ gamma,
                                             const float* __restrict__ beta,
                                             const float* __restrict__ stats,
                                             float* __restrict__ out) {
    __shared__ float Al[6][260], Dl[6][260];
    __shared__ float sc[256], sh[256], bi[256];
    const int t = threadIdx.x;
    const int b = blockIdx.x;
    const unsigned short* ga = AD + (size_t)b * 1536;
    const unsigned short* gd = AD + AD_HALF + (size_t)b * 1536;
#pragma unroll
    for (int i = 0; i < 6; ++i) {
        Al[i][t] = bf2f(ga[i * 256 + t]);
        Dl[i][t] = bf2f(gd[i * 256 + t]);
    }
    const float inv_n = 1.0f / (float)NTOT;
    float mean = stats[t] * inv_n;
    float var = fmaf(-mean, mean, stats[256 + t] * inv_n);
    float scale = gamma[t] * rsqrtf(var + 1e-5f);
    sc[t] = scale;
    sh[t] = fmaf(-mean, scale, beta[t]);
    bi[t] = conv_b[t];
    __syncthreads();
    float* ob = out + (size_t)b * 9216;
#pragma unroll
    for (int it = 0; it < 36; ++it) {
        int idx = it * 256 + t;
        int c = idx / 36;
        int r = idx - c * 36;
        int ii = r / 6;
        int j = r - ii * 6;
        int d = j - ii; if (d < 0) d += 6;
        float h = fmaxf(Al[j][c] + Dl[d][c] + bi[c], 0.f);
        __builtin_nontemporal_store(fmaf(h, sc[c], sh[c]), ob + idx);
    }
}

extern "C" void kernel_launch(void* const* d_in, const int* in_sizes, int n_in,
                              void* d_out, int out_size, void* d_ws, size_t ws_size,
                              hipStream_t stream) {
    const float* x      = (const float*)d_in[0];
    const float* conv_w = (const float*)d_in[1];
    const float* conv_b = (const float*)d_in[2];
    const float* gamma  = (const float*)d_in[3];
    const float* beta   = (const float*)d_in[4];
    float* out = (float*)d_out;

    char* ws = (char*)d_ws;
    unsigned short* wbf = (unsigned short*)ws;                       // 512 KB
    unsigned short* AD  = (unsigned short*)(ws + 524288);            // 25165824 B
    float* stats        = (float*)(ws + 524288 + 25165824);          // 2 KB

    k_pre<<<256, 256, 0, stream>>>(conv_w, wbf, stats);
    k_gemm_fused<<<256, 512, 0, stream>>>(x, wbf, conv_b, AD, stats);
    k_out<<<4096, 256, 0, stream>>>(AD, conv_b, gamma, beta, stats, out);
}